// Round 4
// baseline (350.660 us; speedup 1.0000x reference)
//
#include <hip/hip_runtime.h>
#include <stdint.h>

typedef unsigned short ushort_t;
typedef __attribute__((ext_vector_type(8))) short short8;
typedef __attribute__((ext_vector_type(4))) float f32x4;
typedef __attribute__((ext_vector_type(4))) uint32_t u32x4;

#define B_SZ 8
#define T_SZ 512
#define D_SZ 1024
#define MT 256      // M tile (rows of x per block)
#define NT 64       // N tile (output cols per block)
#define BK 64       // K per step
#define KSTEPS 16   // D / BK
#define CSTRIDE 68  // combine-buffer row stride (fp32)

__device__ __forceinline__ ushort_t f2bf(float f) {
  union { float f; uint32_t i; } c; c.f = f;
  uint32_t u = c.i;
  u += 0x7fffu + ((u >> 16) & 1u);  // RNE
  return (ushort_t)(u >> 16);
}

__device__ __forceinline__ uint32_t pk_bf16(float a, float b) {
#if __has_builtin(__builtin_amdgcn_cvt_pk_bf16_f32)
  typedef __bf16 bf2_t __attribute__((ext_vector_type(2)));
  union { bf2_t v; uint32_t u; } c;
  c.v = __builtin_amdgcn_cvt_pk_bf16_f32(a, b);
  return c.u;
#else
  return (uint32_t)f2bf(a) | ((uint32_t)f2bf(b) << 16);
#endif
}

// 1024 threads = 16 waves (4 waves/SIMD at 1 block/CU — 2x the TLP of r3).
// Waves 0-7: expert slot 0; waves 8-15: slot 1. Each wave: 32x64 strip.
// Block tile 256x64, BK=64/step, double-buffered LDS, 1 barrier/step.
// Grid: bid&7 = batch (XCD-affine: x[b] ~2MB L2-resident), mt(2) x nt(16).
__global__ __launch_bounds__(1024, 4)
void moe_gemm(const float* __restrict__ x, const float* __restrict__ w,
              const float* __restrict__ Wb, const float* __restrict__ bb,
              const int* __restrict__ idx, float* __restrict__ out)
{
  __shared__ union {
    struct {
      ushort_t A[2][MT * BK];       // 2 x 32 KB, XOR-swizzled k-blocks
      ushort_t BT[2][2][NT * BK];   // 2 bufs x 2 experts x 8 KB, [n][k] swizzled
    } st;                           // 96 KB
    float comb[MT * CSTRIDE];       // 68 KB epilogue combine
  } sm;

  const int tid  = threadIdx.x;
  const int lane = tid & 63;
  const int wave = tid >> 6;
  const int grp  = wave >> 3;       // expert slot
  const int wl   = wave & 7;        // 8 waves per slot, 32-row strips

  const int bid = blockIdx.x;
  const int b   = bid & 7;          // XCD-affine batch
  const int rr  = bid >> 3;
  const int mt  = rr >> 4;          // 0..1
  const int nt  = rr & 15;          // 0..15

  const int   e  = idx[b * 2 + grp];
  const float wk = w[b * 2 + grp];
  const float* Wg = Wb + (size_t)e * (D_SZ * (size_t)D_SZ);

  // ---- W staging: 512 threads/group; kg: 32 groups of 2 k-rows, ng: 16 x 4 cols
  const int tl = tid & 511;
  const int kg = tl >> 4;           // 0..31
  const int ng = tl & 15;           // 0..15
  const float* Wrow = Wg + (size_t)(kg * 2) * D_SZ + (nt * NT + ng * 4);

  // ---- A staging: 2 fragments of 8 k-elems per thread (2048 frags / 1024 thr)
  const float* xr[2];
  int aoff[2];
#pragma unroll
  for (int i = 0; i < 2; ++i) {
    const int f  = tid + 1024 * i;
    const int am = f >> 3;          // 0..255
    const int kb = f & 7;
    xr[i]   = x + (size_t)(b * T_SZ + mt * MT + am) * D_SZ + kb * 8;
    aoff[i] = am * BK + (kb ^ (am & 7)) * 8;   // XOR-swizzled k-block slot
  }

  // ---- prologue: step-0 loads (fp32 registers)
  f32x4 areg[4], wreg[2];
#pragma unroll
  for (int i = 0; i < 2; ++i) {
    areg[2 * i + 0] = *(const f32x4*)(xr[i]);
    areg[2 * i + 1] = *(const f32x4*)(xr[i] + 4);
  }
  wreg[0] = *(const f32x4*)(Wrow);
  wreg[1] = *(const f32x4*)(Wrow + D_SZ);

  f32x4 acc[2][4];
#pragma unroll
  for (int mi = 0; mi < 2; ++mi)
#pragma unroll
    for (int ni = 0; ni < 4; ++ni) acc[mi][ni] = (f32x4){0.f, 0.f, 0.f, 0.f};

  const int fm   = lane & 15;
  const int quad = lane >> 4;
  const int mb   = wl * 32;         // wave's 32-row strip

  for (int step = 0; step < KSTEPS; ++step) {
    const int buf = step & 1;
    ushort_t* As = sm.st.A[buf];
    ushort_t* Bt = sm.st.BT[buf][grp];

    // ---- stage: cvt fp32 regs -> bf16 LDS tiles
#pragma unroll
    for (int i = 0; i < 2; ++i) {
      u32x4 av = { pk_bf16(areg[2*i][0],   areg[2*i][1]),
                   pk_bf16(areg[2*i][2],   areg[2*i][3]),
                   pk_bf16(areg[2*i+1][0], areg[2*i+1][1]),
                   pk_bf16(areg[2*i+1][2], areg[2*i+1][3]) };
      *(u32x4*)(As + aoff[i]) = av;
    }
#pragma unroll
    for (int j = 0; j < 4; ++j) {
      const int n = ng * 4 + j;
      const int s = (n ^ (n >> 3)) & 7;
      const int elem = n * BK + (((kg >> 2) ^ s) << 3) + ((kg & 3) << 1);
      *(uint32_t*)(Bt + elem) = pk_bf16(wreg[0][j], wreg[1][j]);
    }
    __syncthreads();   // tiles visible; WAR safe via double buffer

    // ---- prefetch step+1 (hides under MFMA phase)
    if (step + 1 < KSTEPS) {
      const int ko = (step + 1) * BK;
#pragma unroll
      for (int i = 0; i < 2; ++i) {
        areg[2 * i + 0] = *(const f32x4*)(xr[i] + ko);
        areg[2 * i + 1] = *(const f32x4*)(xr[i] + ko + 4);
      }
      const float* p = Wrow + (size_t)ko * D_SZ;
      wreg[0] = *(const f32x4*)(p);
      wreg[1] = *(const f32x4*)(p + D_SZ);
    }

    // ---- MFMA phase: wave computes 32x64 (2x4 16x16 tiles), 16 MFMA/step
#pragma unroll
    for (int h = 0; h < 2; ++h) {
      short8 af[2], bfr[4];
#pragma unroll
      for (int mi = 0; mi < 2; ++mi) {
        const int m = mb + mi * 16 + fm;
        const int kbs = (h * 4 + quad) ^ (m & 7);
        af[mi] = *(const short8*)(As + m * BK + kbs * 8);
      }
#pragma unroll
      for (int ni = 0; ni < 4; ++ni) {
        const int n = ni * 16 + fm;
        const int kbs = (h * 4 + quad) ^ ((n ^ (n >> 3)) & 7);
        bfr[ni] = *(const short8*)(Bt + n * BK + kbs * 8);
      }
#pragma unroll
      for (int mi = 0; mi < 2; ++mi)
#pragma unroll
        for (int ni = 0; ni < 4; ++ni)
          acc[mi][ni] = __builtin_amdgcn_mfma_f32_16x16x32_bf16(af[mi], bfr[ni],
                                                                acc[mi][ni], 0, 0, 0);
    }
  }

  // ---- epilogue: bias + relu + gate
  float bias_v[4];
#pragma unroll
  for (int ni = 0; ni < 4; ++ni)
    bias_v[ni] = bb[e * D_SZ + nt * NT + ni * 16 + fm];

#pragma unroll
  for (int mi = 0; mi < 2; ++mi)
#pragma unroll
    for (int ni = 0; ni < 4; ++ni)
#pragma unroll
      for (int rg = 0; rg < 4; ++rg) {
        float v = acc[mi][ni][rg] + bias_v[ni];
        v = v > 0.f ? v : 0.f;
        acc[mi][ni][rg] = v * wk;
      }

  // ---- combine expert slots via LDS (aliases staging buffers)
  __syncthreads();
  float* comb = sm.comb;
  if (grp == 1) {
#pragma unroll
    for (int mi = 0; mi < 2; ++mi)
#pragma unroll
      for (int ni = 0; ni < 4; ++ni)
#pragma unroll
        for (int rg = 0; rg < 4; ++rg) {
          const int row = mb + mi * 16 + quad * 4 + rg;
          const int col = ni * 16 + fm;
          comb[row * CSTRIDE + col] = acc[mi][ni][rg];
        }
  }
  __syncthreads();
  if (grp == 0) {
#pragma unroll
    for (int mi = 0; mi < 2; ++mi)
#pragma unroll
      for (int ni = 0; ni < 4; ++ni)
#pragma unroll
        for (int rg = 0; rg < 4; ++rg) {
          const int row = mb + mi * 16 + quad * 4 + rg;
          const int col = ni * 16 + fm;
          comb[row * CSTRIDE + col] += acc[mi][ni][rg];
        }
  }
  __syncthreads();

  // ---- coalesced fp32 store: 256x64 tile, 4 float4 per thread
#pragma unroll
  for (int r = 0; r < 4; ++r) {
    const int c   = r * 1024 + tid;    // float4 index
    const int row = c >> 4;            // 16 float4 per row
    const int c4  = c & 15;
    f32x4 v = *(const f32x4*)(comb + row * CSTRIDE + c4 * 4);
    *(f32x4*)(out + (size_t)(b * T_SZ + mt * MT + row) * D_SZ + nt * NT + c4 * 4) = v;
  }
}

extern "C" void kernel_launch(void* const* d_in, const int* in_sizes, int n_in,
                              void* d_out, int out_size, void* d_ws, size_t ws_size,
                              hipStream_t stream) {
  const float* x  = (const float*)d_in[0];
  const float* w  = (const float*)d_in[1];
  const float* Wb = (const float*)d_in[2];
  const float* bb = (const float*)d_in[3];
  const int*   idx = (const int*)d_in[4];
  float* out = (float*)d_out;
  (void)in_sizes; (void)n_in; (void)out_size; (void)d_ws; (void)ws_size;

  dim3 grid(256);    // b(8, low bits -> XCD-affine) x mt(2) x nt(16)
  dim3 block(1024);  // 16 waves: 4 waves/SIMD at 1 block/CU
  hipLaunchKernelGGL(moe_gemm, grid, block, 0, stream, x, w, Wb, bb, idx, out);
}